// Round 1
// baseline (411.288 us; speedup 1.0000x reference)
//
#include <hip/hip_runtime.h>
#include <hip/hip_bf16.h>

#define DMODEL 512
#define NHEADS 8
#define HDIM 64
#define DFF 2048
#define NSEQ 2048
#define BATCH 2
#define NROWS (BATCH * NSEQ)

// ---------------------------------------------------------------------------
// LayerNorm: one wave (64 lanes) per row of 512. Lane l owns elems l*8..l*8+7.
// ---------------------------------------------------------------------------
__global__ __launch_bounds__(64)
void ln_kernel(const float* __restrict__ x, const float* __restrict__ g,
               const float* __restrict__ b, float* __restrict__ out) {
  const int row = blockIdx.x;
  const int lane = threadIdx.x;
  const float* xr = x + (size_t)row * DMODEL + lane * 8;
  const float4 v0 = *(const float4*)(xr);
  const float4 v1 = *(const float4*)(xr + 4);
  float s  = v0.x + v0.y + v0.z + v0.w + v1.x + v1.y + v1.z + v1.w;
  float s2 = v0.x*v0.x + v0.y*v0.y + v0.z*v0.z + v0.w*v0.w
           + v1.x*v1.x + v1.y*v1.y + v1.z*v1.z + v1.w*v1.w;
  #pragma unroll
  for (int m = 1; m < 64; m <<= 1) {
    s  += __shfl_xor(s,  m);
    s2 += __shfl_xor(s2, m);
  }
  const float mu  = s * (1.0f / DMODEL);
  const float var = s2 * (1.0f / DMODEL) - mu * mu;
  const float rs  = rsqrtf(var + 1e-5f);
  const float4 g0 = *(const float4*)(g + lane * 8);
  const float4 g1 = *(const float4*)(g + lane * 8 + 4);
  const float4 b0 = *(const float4*)(b + lane * 8);
  const float4 b1 = *(const float4*)(b + lane * 8 + 4);
  float4 o0, o1;
  o0.x = (v0.x - mu) * rs * g0.x + b0.x;
  o0.y = (v0.y - mu) * rs * g0.y + b0.y;
  o0.z = (v0.z - mu) * rs * g0.z + b0.z;
  o0.w = (v0.w - mu) * rs * g0.w + b0.w;
  o1.x = (v1.x - mu) * rs * g1.x + b1.x;
  o1.y = (v1.y - mu) * rs * g1.y + b1.y;
  o1.z = (v1.z - mu) * rs * g1.z + b1.z;
  o1.w = (v1.w - mu) * rs * g1.w + b1.w;
  float* orow = out + (size_t)row * DMODEL + lane * 8;
  *(float4*)(orow)     = o0;
  *(float4*)(orow + 4) = o1;
}

// ---------------------------------------------------------------------------
// Tiled fp32 GEMM: C[M,N] = A[M,K] @ B[K,N] + bias (+res / +gelu)
// BM=BN=64, BK=16, 256 threads, 4x4 microtile per thread.
// MODE: 0 = +bias, 1 = +bias+res, 2 = +bias+gelu(exact)
// ---------------------------------------------------------------------------
template<int MODE>
__global__ __launch_bounds__(256)
void gemm_kernel(const float* __restrict__ A, const float* __restrict__ B,
                 const float* __restrict__ bias, const float* __restrict__ res,
                 float* __restrict__ C, int M, int N, int K) {
  __shared__ float As[16][64];
  __shared__ float Bs[16][64];
  const int tid = threadIdx.x;
  const int tx = tid & 15, ty = tid >> 4;
  const int bm = blockIdx.y * 64, bn = blockIdx.x * 64;

  float acc[4][4] = {};

  const int arow = tid >> 2;            // 0..63
  const int acol = (tid & 3) * 4;       // 0,4,8,12
  const int brow = tid >> 4;            // 0..15
  const int bcol = (tid & 15) * 4;      // 0..60

  for (int k0 = 0; k0 < K; k0 += 16) {
    const float4 a  = *(const float4*)(A + (size_t)(bm + arow) * K + k0 + acol);
    const float4 bb = *(const float4*)(B + (size_t)(k0 + brow) * N + bn + bcol);
    __syncthreads();
    As[acol + 0][arow] = a.x;
    As[acol + 1][arow] = a.y;
    As[acol + 2][arow] = a.z;
    As[acol + 3][arow] = a.w;
    *(float4*)&Bs[brow][bcol] = bb;
    __syncthreads();
    #pragma unroll
    for (int k = 0; k < 16; ++k) {
      const float4 av = *(const float4*)&As[k][ty << 2];
      const float4 bv = *(const float4*)&Bs[k][tx << 2];
      const float a_[4] = {av.x, av.y, av.z, av.w};
      const float b_[4] = {bv.x, bv.y, bv.z, bv.w};
      #pragma unroll
      for (int i2 = 0; i2 < 4; ++i2)
        #pragma unroll
        for (int j2 = 0; j2 < 4; ++j2)
          acc[i2][j2] = fmaf(a_[i2], b_[j2], acc[i2][j2]);
    }
  }

  #pragma unroll
  for (int i2 = 0; i2 < 4; ++i2) {
    const int row = bm + (ty << 2) + i2;
    const int col = bn + (tx << 2);
    float vv[4];
    #pragma unroll
    for (int j2 = 0; j2 < 4; ++j2) {
      float t = acc[i2][j2] + bias[col + j2];
      if (MODE == 1) t += res[(size_t)row * N + col + j2];
      if (MODE == 2) t = 0.5f * t * (1.0f + erff(t * 0.70710678118654752f));
      vv[j2] = t;
    }
    *(float4*)(C + (size_t)row * N + col) = make_float4(vv[0], vv[1], vv[2], vv[3]);
  }
}

// ---------------------------------------------------------------------------
// Sparse geometric attention. One wave per (b,i) query row, all 8 heads.
// qkv layout per row: [3][8][64] -> q at 0, k at +512, v at +1024.
// mask[i,j] = (lvl_i==lvl_j && |pos_i-pos_j|_1 <= 1 && |i-j| < win(lvl_i)) || i==j
// ---------------------------------------------------------------------------
#define CAP 256
__global__ __launch_bounds__(64)
void attn_kernel(const float* __restrict__ qkv, const int* __restrict__ pos,
                 const int* __restrict__ lvl, float* __restrict__ out) {
  const int r = blockIdx.x;             // b*N + i
  const int i = r & (NSEQ - 1);
  const int base = r - i;               // b*N
  const int lane = threadIdx.x;

  __shared__ int   s_idx[CAP];
  __shared__ int   s_cnt;
  __shared__ float s_sc[NHEADS][CAP];
  __shared__ float s_inv[NHEADS];

  if (lane == 0) s_cnt = 0;
  __syncthreads();

  const int li = lvl[r];
  const int px = pos[2 * r], py = pos[2 * r + 1];
  const int win = (li == 0) ? 512 : (li == 1 ? 64 : 16);
  const int jlo = max(i - win + 1, 0);
  const int jhi = min(i + win - 1, NSEQ - 1);

  for (int j = jlo + lane; j <= jhi; j += 64) {
    const int rj = base + j;
    bool m = (j == i);
    if (!m) {
      const int lj = lvl[rj];
      const int d = abs(px - pos[2 * rj]) + abs(py - pos[2 * rj + 1]);
      m = (lj == li) && (d <= 1);
    }
    if (m) {
      const int p = atomicAdd(&s_cnt, 1);
      if (p < CAP) s_idx[p] = j;
    }
  }
  __syncthreads();
  const int cnt = min(s_cnt, CAP);

  // q fragment: head h = lane>>3, dims (lane&7)*8..+8
  const float* qrow = qkv + (size_t)r * 1536 + lane * 8;
  const float4 q0 = *(const float4*)(qrow);
  const float4 q1 = *(const float4*)(qrow + 4);

  // scores for each matched j
  for (int jj = 0; jj < cnt; ++jj) {
    const int rj = base + s_idx[jj];
    const float* krow = qkv + (size_t)rj * 1536 + 512 + lane * 8;
    const float4 k0 = *(const float4*)(krow);
    const float4 k1 = *(const float4*)(krow + 4);
    float p = q0.x*k0.x + q0.y*k0.y + q0.z*k0.z + q0.w*k0.w
            + q1.x*k1.x + q1.y*k1.y + q1.z*k1.z + q1.w*k1.w;
    p += __shfl_xor(p, 1);
    p += __shfl_xor(p, 2);
    p += __shfl_xor(p, 4);
    if ((lane & 7) == 0) s_sc[lane >> 3][jj] = p * 0.125f;  // 1/sqrt(64)
  }
  __syncthreads();

  // softmax per head (lanes 0..7, one head each); cnt is tiny (usually 1-3)
  if (lane < 8) {
    float mx = -1e30f;
    for (int jj = 0; jj < cnt; ++jj) mx = fmaxf(mx, s_sc[lane][jj]);
    float den = 0.0f;
    for (int jj = 0; jj < cnt; ++jj) {
      const float e = expf(s_sc[lane][jj] - mx);
      s_sc[lane][jj] = e;
      den += e;
    }
    s_inv[lane] = 1.0f / den;
  }
  __syncthreads();

  // PV: lane owns head h = lane>>3, dims (lane&7)*8..+8
  const int h = lane >> 3;
  float a0 = 0, a1 = 0, a2 = 0, a3 = 0, a4 = 0, a5 = 0, a6 = 0, a7 = 0;
  for (int jj = 0; jj < cnt; ++jj) {
    const float pp = s_sc[h][jj];
    const float* vrow = qkv + (size_t)(base + s_idx[jj]) * 1536 + 1024 + lane * 8;
    const float4 v0 = *(const float4*)(vrow);
    const float4 v1 = *(const float4*)(vrow + 4);
    a0 = fmaf(pp, v0.x, a0); a1 = fmaf(pp, v0.y, a1);
    a2 = fmaf(pp, v0.z, a2); a3 = fmaf(pp, v0.w, a3);
    a4 = fmaf(pp, v1.x, a4); a5 = fmaf(pp, v1.y, a5);
    a6 = fmaf(pp, v1.z, a6); a7 = fmaf(pp, v1.w, a7);
  }
  const float inv = s_inv[h];
  float* orow = out + (size_t)r * DMODEL + lane * 8;
  *(float4*)(orow)     = make_float4(a0 * inv, a1 * inv, a2 * inv, a3 * inv);
  *(float4*)(orow + 4) = make_float4(a4 * inv, a5 * inv, a6 * inv, a7 * inv);
}

// ---------------------------------------------------------------------------
extern "C" void kernel_launch(void* const* d_in, const int* in_sizes, int n_in,
                              void* d_out, int out_size, void* d_ws, size_t ws_size,
                              hipStream_t stream) {
  const float* x            = (const float*)d_in[0];
  const int*   coords_pos   = (const int*)d_in[1];
  const int*   coords_level = (const int*)d_in[2];
  const float* w_qkv        = (const float*)d_in[3];
  const float* b_qkv        = (const float*)d_in[4];
  const float* w_out        = (const float*)d_in[5];
  const float* b_out        = (const float*)d_in[6];
  const float* w_ff1        = (const float*)d_in[7];
  const float* b_ff1        = (const float*)d_in[8];
  const float* w_ff2        = (const float*)d_in[9];
  const float* b_ff2        = (const float*)d_in[10];
  const float* ln1_g        = (const float*)d_in[11];
  const float* ln1_b        = (const float*)d_in[12];
  const float* ln2_g        = (const float*)d_in[13];
  const float* ln2_b        = (const float*)d_in[14];
  float* out = (float*)d_out;

  // workspace layout (floats)
  float* ws = (float*)d_ws;
  float* qkv_h    = ws;                       // 4096*1536 (qkv) then 4096*2048 (h) -> 8388608 floats
  float* xn       = qkv_h + 8388608;          // 4096*512, reused for ln1 and ln2 outputs
  float* attn_out = xn + 2097152;             // 4096*512
  float* x1       = attn_out + 2097152;       // 4096*512

  // 1. LN1
  ln_kernel<<<NROWS, 64, 0, stream>>>(x, ln1_g, ln1_b, xn);
  // 2. QKV projection: [4096,512]@[512,1536]
  gemm_kernel<0><<<dim3(1536 / 64, NROWS / 64), 256, 0, stream>>>(
      xn, w_qkv, b_qkv, nullptr, qkv_h, NROWS, 1536, DMODEL);
  // 3. sparse geometric attention
  attn_kernel<<<NROWS, 64, 0, stream>>>(qkv_h, coords_pos, coords_level, attn_out);
  // 4. out projection + residual(x): [4096,512]@[512,512]
  gemm_kernel<1><<<dim3(DMODEL / 64, NROWS / 64), 256, 0, stream>>>(
      attn_out, w_out, b_out, x, x1, NROWS, DMODEL, DMODEL);
  // 5. LN2
  ln_kernel<<<NROWS, 64, 0, stream>>>(x1, ln2_g, ln2_b, xn);
  // 6. FF1 + GELU: [4096,512]@[512,2048]
  gemm_kernel<2><<<dim3(DFF / 64, NROWS / 64), 256, 0, stream>>>(
      xn, w_ff1, b_ff1, nullptr, qkv_h, NROWS, DFF, DMODEL);
  // 7. FF2 + residual(x1): [4096,2048]@[2048,512]
  gemm_kernel<1><<<dim3(DMODEL / 64, NROWS / 64), 256, 0, stream>>>(
      qkv_h, w_ff2, b_ff2, x1, out, NROWS, DMODEL, DFF);
}

// Round 2
// 128.937 us; speedup vs baseline: 3.1898x; 3.1898x over previous
//
#include <hip/hip_runtime.h>
#include <hip/hip_bf16.h>

#define DMODEL 512
#define NHEADS 8
#define HDIM 64
#define DFF 2048
#define NSEQ 2048
#define BATCH 2
#define NROWS (BATCH * NSEQ)

typedef __attribute__((ext_vector_type(8))) short   bf16x8;   // MFMA A/B frag (8 bf16)
typedef __attribute__((ext_vector_type(4))) float   f32x4;    // MFMA C/D frag
typedef __attribute__((ext_vector_type(8))) unsigned short u16x8;

__device__ __forceinline__ unsigned short f2bf(float f) {
  union { float f; unsigned u; } v; v.f = f;
  unsigned r = v.u + 0x7fffu + ((v.u >> 16) & 1u);   // RNE
  return (unsigned short)(r >> 16);
}

#define GLL16(src, dst) \
  __builtin_amdgcn_global_load_lds((__attribute__((address_space(1))) const void*)(src), \
                                   (__attribute__((address_space(3))) void*)(dst), 16, 0, 0)

// ---------------------------------------------------------------------------
// LayerNorm: one wave per row of 512, bf16 output.
// ---------------------------------------------------------------------------
__global__ __launch_bounds__(64)
void ln_kernel(const float* __restrict__ x, const float* __restrict__ g,
               const float* __restrict__ b, unsigned short* __restrict__ out) {
  const int row = blockIdx.x;
  const int lane = threadIdx.x;
  const float* xr = x + (size_t)row * DMODEL + lane * 8;
  const float4 v0 = *(const float4*)(xr);
  const float4 v1 = *(const float4*)(xr + 4);
  float s  = v0.x + v0.y + v0.z + v0.w + v1.x + v1.y + v1.z + v1.w;
  float s2 = v0.x*v0.x + v0.y*v0.y + v0.z*v0.z + v0.w*v0.w
           + v1.x*v1.x + v1.y*v1.y + v1.z*v1.z + v1.w*v1.w;
  #pragma unroll
  for (int m = 1; m < 64; m <<= 1) {
    s  += __shfl_xor(s,  m);
    s2 += __shfl_xor(s2, m);
  }
  const float mu  = s * (1.0f / DMODEL);
  const float var = s2 * (1.0f / DMODEL) - mu * mu;
  const float rs  = rsqrtf(var + 1e-5f);
  const float4 g0 = *(const float4*)(g + lane * 8);
  const float4 g1 = *(const float4*)(g + lane * 8 + 4);
  const float4 b0 = *(const float4*)(b + lane * 8);
  const float4 b1 = *(const float4*)(b + lane * 8 + 4);
  u16x8 o;
  o[0] = f2bf((v0.x - mu) * rs * g0.x + b0.x);
  o[1] = f2bf((v0.y - mu) * rs * g0.y + b0.y);
  o[2] = f2bf((v0.z - mu) * rs * g0.z + b0.z);
  o[3] = f2bf((v0.w - mu) * rs * g0.w + b0.w);
  o[4] = f2bf((v1.x - mu) * rs * g1.x + b1.x);
  o[5] = f2bf((v1.y - mu) * rs * g1.y + b1.y);
  o[6] = f2bf((v1.z - mu) * rs * g1.z + b1.z);
  o[7] = f2bf((v1.w - mu) * rs * g1.w + b1.w);
  *(u16x8*)(out + (size_t)row * DMODEL + lane * 8) = o;
}

// ---------------------------------------------------------------------------
// Weight transpose + fp32->bf16: w[K,N] -> wT[N,K]
// ---------------------------------------------------------------------------
__global__ __launch_bounds__(256)
void wt_kernel(const float* __restrict__ w, unsigned short* __restrict__ wT,
               int K, int N) {
  __shared__ unsigned short t[32][33];
  const int n0 = blockIdx.x * 32, k0 = blockIdx.y * 32;
  const int tx = threadIdx.x, ty = threadIdx.y;
  #pragma unroll
  for (int i = 0; i < 4; ++i)
    t[ty + i * 8][tx] = f2bf(w[(size_t)(k0 + ty + i * 8) * N + n0 + tx]);
  __syncthreads();
  #pragma unroll
  for (int i = 0; i < 4; ++i)
    wT[(size_t)(n0 + ty + i * 8) * K + k0 + tx] = t[tx][ty + i * 8];
}

// ---------------------------------------------------------------------------
// bf16 MFMA GEMM: C[M,N] = A[M,K] @ Bt[N,K]^T + bias (+res / +gelu)
// 128x128 tile, BK=32, 256 threads (4 waves 2x2, each 64x64), double-buffered
// LDS staged via global_load_lds width=16.
// MODE: 0 = +bias (fp32 out), 1 = +bias+res (fp32 out), 2 = +bias+gelu (bf16 out)
// ---------------------------------------------------------------------------
template<int MODE>
__global__ __launch_bounds__(256)
void gemm_bf16(const unsigned short* __restrict__ A,
               const unsigned short* __restrict__ Bt,
               const float* __restrict__ bias, const float* __restrict__ res,
               void* __restrict__ Cout, int M, int N, int K) {
  __shared__ ushort As[2][128 * 32];
  __shared__ ushort Bs[2][128 * 32];

  const int tid = threadIdx.x;
  const int w = tid >> 6;        // wave 0..3
  const int l = tid & 63;
  const int bm = blockIdx.y * 128, bn = blockIdx.x * 128;
  const int wr = (w >> 1) * 64, wc = (w & 1) * 64;   // wave sub-tile origin

  f32x4 acc[4][4] = {};

  // staging: 512 chunks of 16B per tile; wave-uniform LDS base + lane*16
  auto stage = [&](int buf, int k0) {
    #pragma unroll
    for (int rep = 0; rep < 2; ++rep) {
      const int c = (rep * 4 + w) * 64 + l;        // chunk 0..511
      const int row = c >> 2;
      const int kk = (c & 3) * 8;
      const ushort* lbaseA = &As[buf][0] + (rep * 4 + w) * 512;  // 64 chunks * 8 elems
      const ushort* lbaseB = &Bs[buf][0] + (rep * 4 + w) * 512;
      GLL16(A  + (size_t)(bm + row) * K + k0 + kk, lbaseA);
      GLL16(Bt + (size_t)(bn + row) * K + k0 + kk, lbaseB);
    }
  };

  const int nt = K >> 5;
  stage(0, 0);
  int cur = 0;
  const int lr = l & 15, kg = l >> 4;

  for (int t = 0; t < nt; ++t) {
    __syncthreads();                       // drains vmcnt -> buf[cur] ready
    if (t + 1 < nt) stage(cur ^ 1, (t + 1) << 5);
    bf16x8 af[4], bfv[4];
    #pragma unroll
    for (int mi = 0; mi < 4; ++mi)
      af[mi] = *(const bf16x8*)&As[cur][(wr + mi * 16 + lr) * 32 + kg * 8];
    #pragma unroll
    for (int ni = 0; ni < 4; ++ni)
      bfv[ni] = *(const bf16x8*)&Bs[cur][(wc + ni * 16 + lr) * 32 + kg * 8];
    #pragma unroll
    for (int mi = 0; mi < 4; ++mi)
      #pragma unroll
      for (int ni = 0; ni < 4; ++ni)
        acc[mi][ni] = __builtin_amdgcn_mfma_f32_16x16x32_bf16(
            af[mi], bfv[ni], acc[mi][ni], 0, 0, 0);
    cur ^= 1;
  }

  // epilogue: C/D layout col=lane&15, row=(lane>>4)*4+reg
  float* Cf = (float*)Cout;
  unsigned short* Cb = (unsigned short*)Cout;
  #pragma unroll
  for (int mi = 0; mi < 4; ++mi) {
    #pragma unroll
    for (int ni = 0; ni < 4; ++ni) {
      const int gcol = bn + wc + ni * 16 + lr;
      const int grow0 = bm + wr + mi * 16 + kg * 4;
      const float bv = bias[gcol];
      #pragma unroll
      for (int reg = 0; reg < 4; ++reg) {
        const int grow = grow0 + reg;
        float t = acc[mi][ni][reg] + bv;
        if (MODE == 1) t += res[(size_t)grow * N + gcol];
        if (MODE == 2) {
          t = 0.5f * t * (1.0f + erff(t * 0.70710678118654752f));
          Cb[(size_t)grow * N + gcol] = f2bf(t);
        } else {
          Cf[(size_t)grow * N + gcol] = t;
        }
      }
    }
  }
}

// ---------------------------------------------------------------------------
// Sparse geometric attention (unchanged math), bf16 output.
// ---------------------------------------------------------------------------
#define CAP 256
__global__ __launch_bounds__(64)
void attn_kernel(const float* __restrict__ qkv, const int* __restrict__ pos,
                 const int* __restrict__ lvl, unsigned short* __restrict__ out) {
  const int r = blockIdx.x;
  const int i = r & (NSEQ - 1);
  const int base = r - i;
  const int lane = threadIdx.x;

  __shared__ int   s_idx[CAP];
  __shared__ int   s_cnt;
  __shared__ float s_sc[NHEADS][CAP];
  __shared__ float s_inv[NHEADS];

  if (lane == 0) s_cnt = 0;
  __syncthreads();

  const int li = lvl[r];
  const int px = pos[2 * r], py = pos[2 * r + 1];
  const int win = (li == 0) ? 512 : (li == 1 ? 64 : 16);
  const int jlo = max(i - win + 1, 0);
  const int jhi = min(i + win - 1, NSEQ - 1);

  for (int j = jlo + lane; j <= jhi; j += 64) {
    const int rj = base + j;
    bool m = (j == i);
    if (!m) {
      const int lj = lvl[rj];
      const int d = abs(px - pos[2 * rj]) + abs(py - pos[2 * rj + 1]);
      m = (lj == li) && (d <= 1);
    }
    if (m) {
      const int p = atomicAdd(&s_cnt, 1);
      if (p < CAP) s_idx[p] = j;
    }
  }
  __syncthreads();
  const int cnt = min(s_cnt, CAP);

  const float* qrow = qkv + (size_t)r * 1536 + lane * 8;
  const float4 q0 = *(const float4*)(qrow);
  const float4 q1 = *(const float4*)(qrow + 4);

  for (int jj = 0; jj < cnt; ++jj) {
    const int rj = base + s_idx[jj];
    const float* krow = qkv + (size_t)rj * 1536 + 512 + lane * 8;
    const float4 k0 = *(const float4*)(krow);
    const float4 k1 = *(const float4*)(krow + 4);
    float p = q0.x*k0.x + q0.y*k0.y + q0.z*k0.z + q0.w*k0.w
            + q1.x*k1.x + q1.y*k1.y + q1.z*k1.z + q1.w*k1.w;
    p += __shfl_xor(p, 1);
    p += __shfl_xor(p, 2);
    p += __shfl_xor(p, 4);
    if ((lane & 7) == 0) s_sc[lane >> 3][jj] = p * 0.125f;
  }
  __syncthreads();

  if (lane < 8) {
    float mx = -1e30f;
    for (int jj = 0; jj < cnt; ++jj) mx = fmaxf(mx, s_sc[lane][jj]);
    float den = 0.0f;
    for (int jj = 0; jj < cnt; ++jj) {
      const float e = expf(s_sc[lane][jj] - mx);
      s_sc[lane][jj] = e;
      den += e;
    }
    s_inv[lane] = 1.0f / den;
  }
  __syncthreads();

  const int h = lane >> 3;
  float a0 = 0, a1 = 0, a2 = 0, a3 = 0, a4 = 0, a5 = 0, a6 = 0, a7 = 0;
  for (int jj = 0; jj < cnt; ++jj) {
    const float pp = s_sc[h][jj];
    const float* vrow = qkv + (size_t)(base + s_idx[jj]) * 1536 + 1024 + lane * 8;
    const float4 v0 = *(const float4*)(vrow);
    const float4 v1 = *(const float4*)(vrow + 4);
    a0 = fmaf(pp, v0.x, a0); a1 = fmaf(pp, v0.y, a1);
    a2 = fmaf(pp, v0.z, a2); a3 = fmaf(pp, v0.w, a3);
    a4 = fmaf(pp, v1.x, a4); a5 = fmaf(pp, v1.y, a5);
    a6 = fmaf(pp, v1.z, a6); a7 = fmaf(pp, v1.w, a7);
  }
  const float inv = s_inv[h];
  u16x8 o;
  o[0] = f2bf(a0 * inv); o[1] = f2bf(a1 * inv);
  o[2] = f2bf(a2 * inv); o[3] = f2bf(a3 * inv);
  o[4] = f2bf(a4 * inv); o[5] = f2bf(a5 * inv);
  o[6] = f2bf(a6 * inv); o[7] = f2bf(a7 * inv);
  *(u16x8*)(out + (size_t)r * DMODEL + lane * 8) = o;
}

// ---------------------------------------------------------------------------
extern "C" void kernel_launch(void* const* d_in, const int* in_sizes, int n_in,
                              void* d_out, int out_size, void* d_ws, size_t ws_size,
                              hipStream_t stream) {
  const float* x            = (const float*)d_in[0];
  const int*   coords_pos   = (const int*)d_in[1];
  const int*   coords_level = (const int*)d_in[2];
  const float* w_qkv        = (const float*)d_in[3];
  const float* b_qkv        = (const float*)d_in[4];
  const float* w_out        = (const float*)d_in[5];
  const float* b_out        = (const float*)d_in[6];
  const float* w_ff1        = (const float*)d_in[7];
  const float* b_ff1        = (const float*)d_in[8];
  const float* w_ff2        = (const float*)d_in[9];
  const float* b_ff2        = (const float*)d_in[10];
  const float* ln1_g        = (const float*)d_in[11];
  const float* ln1_b        = (const float*)d_in[12];
  const float* ln2_g        = (const float*)d_in[13];
  const float* ln2_b        = (const float*)d_in[14];
  float* out = (float*)d_out;

  // workspace layout (bytes)
  char* ws = (char*)d_ws;
  float*          qkv_f  = (float*)(ws);                      // 4096*1536*4 = 25165824
  unsigned short* h_bf   = (unsigned short*)(ws);             // reuses qkv region (16.8MB)
  float*          x1     = (float*)(ws + 25165824);           // 8388608
  unsigned short* xn_bf  = (unsigned short*)(ws + 33554432);  // 4194304
  unsigned short* at_bf  = (unsigned short*)(ws + 37748736);  // 4194304
  unsigned short* wqkvT  = (unsigned short*)(ws + 41943040);  // 1572864
  unsigned short* woutT  = (unsigned short*)(ws + 43515904);  // 524288
  unsigned short* wff1T  = (unsigned short*)(ws + 44040192);  // 2097152
  unsigned short* wff2T  = (unsigned short*)(ws + 46137344);  // 2097152

  // weight transpose + cast
  wt_kernel<<<dim3(1536/32, 512/32),  dim3(32,8), 0, stream>>>(w_qkv, wqkvT, 512, 1536);
  wt_kernel<<<dim3(512/32,  512/32),  dim3(32,8), 0, stream>>>(w_out, woutT, 512, 512);
  wt_kernel<<<dim3(2048/32, 512/32),  dim3(32,8), 0, stream>>>(w_ff1, wff1T, 512, 2048);
  wt_kernel<<<dim3(512/32,  2048/32), dim3(32,8), 0, stream>>>(w_ff2, wff2T, 2048, 512);

  // 1. LN1 -> bf16
  ln_kernel<<<NROWS, 64, 0, stream>>>(x, ln1_g, ln1_b, xn_bf);
  // 2. QKV projection (fp32 out)
  gemm_bf16<0><<<dim3(1536/128, NROWS/128), 256, 0, stream>>>(
      xn_bf, wqkvT, b_qkv, nullptr, qkv_f, NROWS, 1536, DMODEL);
  // 3. sparse geometric attention -> bf16
  attn_kernel<<<NROWS, 64, 0, stream>>>(qkv_f, coords_pos, coords_level, at_bf);
  // 4. out projection + residual(x) -> fp32 x1
  gemm_bf16<1><<<dim3(DMODEL/128, NROWS/128), 256, 0, stream>>>(
      at_bf, woutT, b_out, x, x1, NROWS, DMODEL, DMODEL);
  // 5. LN2 -> bf16
  ln_kernel<<<NROWS, 64, 0, stream>>>(x1, ln2_g, ln2_b, xn_bf);
  // 6. FF1 + GELU -> bf16 (into qkv region, qkv no longer needed)
  gemm_bf16<2><<<dim3(DFF/128, NROWS/128), 256, 0, stream>>>(
      xn_bf, wff1T, b_ff1, nullptr, h_bf, NROWS, DFF, DMODEL);
  // 7. FF2 + residual(x1) -> d_out
  gemm_bf16<1><<<dim3(DMODEL/128, NROWS/128), 256, 0, stream>>>(
      h_bf, wff2T, b_ff2, x1, out, NROWS, DMODEL, DFF);
}